// Round 2
// baseline (297.605 us; speedup 1.0000x reference)
//
#include <hip/hip_runtime.h>

typedef __attribute__((ext_vector_type(4))) int int4v;
typedef __attribute__((ext_vector_type(16))) int int16v;

#define NPIX 100352      // 32*56*56
#define KTAP 2304        // 9*256
#define LDK 144          // 128 + 16 pad (16B aligned for ds b128)

// ---------- kernel 1: weight sign (transposed to [cout][k]) + sum|W| ----------
__global__ __launch_bounds__(256) void quant_w_kernel(const float* __restrict__ Wm,
                                                      signed char* __restrict__ Bt,
                                                      float* __restrict__ Esum) {
  int j4 = blockIdx.x * 256 + threadIdx.x;   // 147456 threads, 4 bytes each
  int byte0 = j4 * 4;
  int cout = byte0 / KTAP;
  int k0 = byte0 - cout * KTAP;
  float s = 0.f;
  unsigned int packed = 0;
#pragma unroll
  for (int i = 0; i < 4; ++i) {
    float w = Wm[(k0 + i) * 256 + cout];     // W is [k][cout], k=(kh*3+kw)*256+cin
    s += fabsf(w);
    int sg = (w > 0.f) ? 1 : ((w < 0.f) ? -1 : 0);
    packed |= ((unsigned int)(sg & 0xFF)) << (8 * i);
  }
  ((unsigned int*)Bt)[j4] = packed;
#pragma unroll
  for (int o = 32; o > 0; o >>= 1) s += __shfl_down(s, o, 64);
  if ((threadIdx.x & 63) == 0) atomicAdd(Esum, s);
}

// ---------- kernel 2: activation quantize fp32 -> int8 in {0..7} ----------
__global__ __launch_bounds__(256) void quant_x_kernel(const float* __restrict__ x,
                                                      signed char* __restrict__ xq) {
  int t = blockIdx.x * 256 + threadIdx.x;    // 6,422,528 threads
  float4 v = ((const float4*)x)[t];
  unsigned int q = 0;
  q |= (unsigned int)(int)rintf(fminf(1.f, fabsf(v.x)) * 7.f);
  q |= ((unsigned int)(int)rintf(fminf(1.f, fabsf(v.y)) * 7.f)) << 8;
  q |= ((unsigned int)(int)rintf(fminf(1.f, fabsf(v.z)) * 7.f)) << 16;
  q |= ((unsigned int)(int)rintf(fminf(1.f, fabsf(v.w)) * 7.f)) << 24;
  ((unsigned int*)xq)[t] = q;
}

// ---------- kernel 3: implicit-GEMM conv via i8 MFMA ----------
__global__ __launch_bounds__(256) void conv_kernel(const signed char* __restrict__ xq,
                                                   const signed char* __restrict__ Bt,
                                                   const float* __restrict__ bias,
                                                   const float* __restrict__ Esum,
                                                   float* __restrict__ out) {
  __shared__ signed char As[128 * LDK];
  __shared__ signed char Bs[128 * LDK];

  const int t = threadIdx.x;
  const int lane = t & 63;
  const int m0 = blockIdx.x * 128;           // 784 blocks in M
  const int n0 = blockIdx.y * 128;           // 2 blocks in N
  const int wid = t >> 6;
  const int wm = (wid & 1) * 64;
  const int wn = (wid >> 1) * 64;

  // staging mapping: thread covers 4 rows (rbase+32i), 16B column chunk colb
  const int rbase = t >> 3;
  const int colb = (t & 7) * 16;

  int pix[4], hh[4], ww[4];
#pragma unroll
  for (int i = 0; i < 4; ++i) {
    int p = m0 + rbase + 32 * i;
    pix[i] = p;
    int rem = p % 3136;
    hh[i] = rem / 56;
    ww[i] = rem % 56;
  }

  int16v acc[2][2];
#pragma unroll
  for (int a = 0; a < 2; ++a)
#pragma unroll
    for (int b = 0; b < 2; ++b)
#pragma unroll
      for (int r = 0; r < 16; ++r) acc[a][b][r] = 0;

  const int lrow = lane & 31;
  const int khalf = (lane >> 5) * 16;

  for (int tap = 0; tap < 9; ++tap) {
    const int dh = tap / 3 - 1;
    const int dw = tap % 3 - 1;
#pragma unroll
    for (int half = 0; half < 2; ++half) {
      const int kofs = tap * 256 + half * 128;  // K-index into weight matrix
      const int cofs = half * 128;              // channel offset into xq (FIX: no tap*256!)
      __syncthreads();
      // stage A (shifted xq block, zero for SAME-padding rows)
#pragma unroll
      for (int i = 0; i < 4; ++i) {
        const int r = rbase + 32 * i;
        int4v a = {0, 0, 0, 0};
        if ((unsigned)(hh[i] + dh) < 56u && (unsigned)(ww[i] + dw) < 56u) {
          a = *(const int4v*)(xq + (long)(pix[i] + dh * 56 + dw) * 256 + cofs + colb);
        }
        *(int4v*)(As + r * LDK + colb) = a;
      }
      // stage B (sign matrix, [cout][k] layout so frag reads are K-contiguous)
#pragma unroll
      for (int i = 0; i < 4; ++i) {
        const int r = rbase + 32 * i;
        int4v b = *(const int4v*)(Bt + (long)(n0 + r) * KTAP + kofs + colb);
        *(int4v*)(Bs + r * LDK + colb) = b;
      }
      __syncthreads();
#pragma unroll
      for (int ks = 0; ks < 4; ++ks) {
        const int ko = ks * 32 + khalf;
        int4v a0 = *(const int4v*)(As + (wm + lrow) * LDK + ko);
        int4v a1 = *(const int4v*)(As + (wm + 32 + lrow) * LDK + ko);
        int4v b0 = *(const int4v*)(Bs + (wn + lrow) * LDK + ko);
        int4v b1 = *(const int4v*)(Bs + (wn + 32 + lrow) * LDK + ko);
        acc[0][0] = __builtin_amdgcn_mfma_i32_32x32x32_i8(a0, b0, acc[0][0], 0, 0, 0);
        acc[0][1] = __builtin_amdgcn_mfma_i32_32x32x32_i8(a0, b1, acc[0][1], 0, 0, 0);
        acc[1][0] = __builtin_amdgcn_mfma_i32_32x32x32_i8(a1, b0, acc[1][0], 0, 0, 0);
        acc[1][1] = __builtin_amdgcn_mfma_i32_32x32x32_i8(a1, b1, acc[1][1], 0, 0, 0);
      }
    }
  }

  // epilogue: out = acc * (E/7) + bias
  const float scale = Esum[0] * (1.0f / (589824.0f * 7.0f));
#pragma unroll
  for (int mt = 0; mt < 2; ++mt)
#pragma unroll
    for (int nt = 0; nt < 2; ++nt) {
      const int col = n0 + wn + nt * 32 + lrow;
      const float bv = bias[col];
#pragma unroll
      for (int r = 0; r < 16; ++r) {
        const int row = (r & 3) + 8 * (r >> 2) + 4 * (lane >> 5);
        const int m = m0 + wm + mt * 32 + row;
        out[(long)m * 256 + col] = (float)acc[mt][nt][r] * scale + bv;
      }
    }
}

extern "C" void kernel_launch(void* const* d_in, const int* in_sizes, int n_in,
                              void* d_out, int out_size, void* d_ws, size_t ws_size,
                              hipStream_t stream) {
  const float* x    = (const float*)d_in[0];
  const float* Wm   = (const float*)d_in[1];
  const float* bias = (const float*)d_in[2];
  float* out = (float*)d_out;

  float* Esum = (float*)d_ws;
  signed char* Bt = (signed char*)d_ws + 256;                 // 589,824 B
  signed char* xq = (signed char*)d_ws + 256 + 589824;        // 25,690,112 B

  hipMemsetAsync(d_ws, 0, 4, stream);                          // zero E accumulator
  quant_w_kernel<<<576, 256, 0, stream>>>(Wm, Bt, Esum);
  quant_x_kernel<<<25088, 256, 0, stream>>>(x, xq);
  conv_kernel<<<dim3(784, 2), 256, 0, stream>>>(xq, Bt, bias, Esum, out);
}

// Round 3
// 249.189 us; speedup vs baseline: 1.1943x; 1.1943x over previous
//
#include <hip/hip_runtime.h>

typedef __attribute__((ext_vector_type(4))) int int4v;
typedef __attribute__((ext_vector_type(16))) int int16v;

#define NPIX 100352      // 32*56*56
#define KTAP 2304        // 9*256
#define LDK 144          // 128 + 16 pad (16B aligned, measured 0 bank conflicts)

// ---------- kernel 1: weight sign transpose (coalesced reads, LDS transpose) ----------
__global__ __launch_bounds__(256) void quant_w_kernel(const float* __restrict__ Wm,
                                                      signed char* __restrict__ Bt,
                                                      float* __restrict__ Esum) {
  __shared__ signed char sT[64][80];   // [cout][k] tile, row stride 80 (16B aligned)
  __shared__ float red[4];
  const int k0 = blockIdx.x * 64;      // 36 tiles in k
  const int c0 = blockIdx.y * 64;      // 4 tiles in cout
  const int t = threadIdx.x;
  const int cc = t & 63;
  const int r0 = (t >> 6) * 16;
  float s = 0.f;
#pragma unroll
  for (int i = 0; i < 16; ++i) {
    const int k = r0 + i;
    float w = Wm[(long)(k0 + k) * 256 + c0 + cc];   // coalesced over cc
    s += fabsf(w);
    sT[cc][k] = (signed char)((w > 0.f) ? 1 : ((w < 0.f) ? -1 : 0));
  }
#pragma unroll
  for (int o = 32; o > 0; o >>= 1) s += __shfl_down(s, o, 64);
  if ((t & 63) == 0) red[t >> 6] = s;
  __syncthreads();
  if (t == 0) atomicAdd(Esum, red[0] + red[1] + red[2] + red[3]);
  const int co = t >> 2;
  const int kc = (t & 3) * 16;
  int4v v = *(const int4v*)&sT[co][kc];
  *(int4v*)(Bt + (long)(c0 + co) * KTAP + k0 + kc) = v;
}

// ---------- kernel 2: activation quantize fp32 -> int8 in {0..7} ----------
__global__ __launch_bounds__(256) void quant_x_kernel(const float* __restrict__ x,
                                                      signed char* __restrict__ xq) {
  int t = blockIdx.x * 256 + threadIdx.x;    // 6,422,528 threads
  float4 v = ((const float4*)x)[t];
  unsigned int q = 0;
  q |= (unsigned int)(int)rintf(fminf(1.f, fabsf(v.x)) * 7.f);
  q |= ((unsigned int)(int)rintf(fminf(1.f, fabsf(v.y)) * 7.f)) << 8;
  q |= ((unsigned int)(int)rintf(fminf(1.f, fabsf(v.z)) * 7.f)) << 16;
  q |= ((unsigned int)(int)rintf(fminf(1.f, fabsf(v.w)) * 7.f)) << 24;
  ((unsigned int*)xq)[t] = q;
}

// ---------- kernel 3: implicit-GEMM conv, BM=128 BN=256 BK=128, reg-prefetch pipeline ----------
__global__ __launch_bounds__(256, 2) void conv_kernel(const signed char* __restrict__ xq,
                                                      const signed char* __restrict__ Bt,
                                                      const float* __restrict__ bias,
                                                      const float* __restrict__ Esum,
                                                      float* __restrict__ out) {
  __shared__ signed char As[128 * LDK];   // 18,432 B
  __shared__ signed char Bs[256 * LDK];   // 36,864 B

  const int t = threadIdx.x;
  const int lane = t & 63;
  const int wid = t >> 6;
  const int m0 = blockIdx.x * 128;         // 784 blocks
  const int wm = (wid & 1) * 64;           // wave tile: 64 rows x 128 cols
  const int wn = (wid >> 1) * 128;

  const int rbase = t >> 3;                // staging: row group, 16B chunk
  const int colb = (t & 7) * 16;

  // per-row pixel bases + 9-bit tap validity masks (A rows: rbase+32i)
  int abase[4];
  unsigned avalid[4];
#pragma unroll
  for (int i = 0; i < 4; ++i) {
    const int p = m0 + rbase + 32 * i;
    const int rem = p % 3136;
    const int h = rem / 56, w = rem % 56;
    abase[i] = p * 256 + colb;
    unsigned mask = 0;
#pragma unroll
    for (int tap = 0; tap < 9; ++tap) {
      const int dh = tap / 3 - 1, dw = tap % 3 - 1;
      if ((unsigned)(h + dh) < 56u && (unsigned)(w + dw) < 56u) mask |= 1u << tap;
    }
    avalid[i] = mask;
  }
  int bofs[8];
#pragma unroll
  for (int i = 0; i < 8; ++i) bofs[i] = (rbase + 32 * i) * KTAP + colb;

  int16v acc[2][4];
#pragma unroll
  for (int a = 0; a < 2; ++a)
#pragma unroll
    for (int b = 0; b < 4; ++b)
#pragma unroll
      for (int r = 0; r < 16; ++r) acc[a][b][r] = 0;

  int4v ra[4], rb[8];

  auto prefetch = [&](int s) {
    const int tap = s >> 1, hf = s & 1;
    const int dh = tap / 3 - 1, dw = tap % 3 - 1;
    const int shift = (dh * 56 + dw) * 256 + hf * 128;  // into xq (channels only)
    const int kofs = tap * 256 + hf * 128;              // into weight K
#pragma unroll
    for (int i = 0; i < 4; ++i) {
      int4v a = {0, 0, 0, 0};
      if (avalid[i] & (1u << tap)) a = *(const int4v*)(xq + (long)(abase[i] + shift));
      ra[i] = a;
    }
#pragma unroll
    for (int i = 0; i < 8; ++i) rb[i] = *(const int4v*)(Bt + (long)(bofs[i] + kofs));
  };

  prefetch(0);
  const int lrow = lane & 31;
  const int khalf = (lane >> 5) * 16;

  for (int s = 0; s < 18; ++s) {
    if (s) __syncthreads();                 // all waves done reading previous LDS
#pragma unroll
    for (int i = 0; i < 4; ++i)
      *(int4v*)(As + (rbase + 32 * i) * LDK + colb) = ra[i];
#pragma unroll
    for (int i = 0; i < 8; ++i)
      *(int4v*)(Bs + (rbase + 32 * i) * LDK + colb) = rb[i];
    __syncthreads();
    if (s + 1 < 18) prefetch(s + 1);        // loads fly during MFMA block below
#pragma unroll
    for (int ks = 0; ks < 4; ++ks) {
      const int ko = ks * 32 + khalf;
      int4v a0 = *(const int4v*)(As + (wm + lrow) * LDK + ko);
      int4v a1 = *(const int4v*)(As + (wm + 32 + lrow) * LDK + ko);
      int4v b0 = *(const int4v*)(Bs + (wn + lrow) * LDK + ko);
      int4v b1 = *(const int4v*)(Bs + (wn + 32 + lrow) * LDK + ko);
      int4v b2 = *(const int4v*)(Bs + (wn + 64 + lrow) * LDK + ko);
      int4v b3 = *(const int4v*)(Bs + (wn + 96 + lrow) * LDK + ko);
      acc[0][0] = __builtin_amdgcn_mfma_i32_32x32x32_i8(a0, b0, acc[0][0], 0, 0, 0);
      acc[0][1] = __builtin_amdgcn_mfma_i32_32x32x32_i8(a0, b1, acc[0][1], 0, 0, 0);
      acc[0][2] = __builtin_amdgcn_mfma_i32_32x32x32_i8(a0, b2, acc[0][2], 0, 0, 0);
      acc[0][3] = __builtin_amdgcn_mfma_i32_32x32x32_i8(a0, b3, acc[0][3], 0, 0, 0);
      acc[1][0] = __builtin_amdgcn_mfma_i32_32x32x32_i8(a1, b0, acc[1][0], 0, 0, 0);
      acc[1][1] = __builtin_amdgcn_mfma_i32_32x32x32_i8(a1, b1, acc[1][1], 0, 0, 0);
      acc[1][2] = __builtin_amdgcn_mfma_i32_32x32x32_i8(a1, b2, acc[1][2], 0, 0, 0);
      acc[1][3] = __builtin_amdgcn_mfma_i32_32x32x32_i8(a1, b3, acc[1][3], 0, 0, 0);
    }
  }

  // epilogue: out = acc * (E/7) + bias
  const float scale = Esum[0] * (1.0f / (589824.0f * 7.0f));
#pragma unroll
  for (int mt = 0; mt < 2; ++mt)
#pragma unroll
    for (int nt = 0; nt < 4; ++nt) {
      const int col = wn + nt * 32 + lrow;
      const float bv = bias[col];
#pragma unroll
      for (int r = 0; r < 16; ++r) {
        const int row = (r & 3) + 8 * (r >> 2) + 4 * (lane >> 5);
        const int m = m0 + wm + mt * 32 + row;
        out[(long)m * 256 + col] = (float)acc[mt][nt][r] * scale + bv;
      }
    }
}

extern "C" void kernel_launch(void* const* d_in, const int* in_sizes, int n_in,
                              void* d_out, int out_size, void* d_ws, size_t ws_size,
                              hipStream_t stream) {
  const float* x    = (const float*)d_in[0];
  const float* Wm   = (const float*)d_in[1];
  const float* bias = (const float*)d_in[2];
  float* out = (float*)d_out;

  float* Esum = (float*)d_ws;
  signed char* Bt = (signed char*)d_ws + 256;                 // 589,824 B
  signed char* xq = (signed char*)d_ws + 256 + 589824;        // 25,690,112 B

  hipMemsetAsync(d_ws, 0, 4, stream);
  quant_w_kernel<<<dim3(36, 4), 256, 0, stream>>>(Wm, Bt, Esum);
  quant_x_kernel<<<25088, 256, 0, stream>>>(x, xq);
  conv_kernel<<<784, 256, 0, stream>>>(xq, Bt, bias, Esum, out);
}